// Round 1
// baseline (529.300 us; speedup 1.0000x reference)
//
#include <hip/hip_runtime.h>
#include <hip/hip_bf16.h>

typedef short bf16x8 __attribute__((ext_vector_type(8)));
typedef float f32x4 __attribute__((ext_vector_type(4)));

#define AS1(p) (const __attribute__((address_space(1))) void*)(p)
#define AS3(p) (__attribute__((address_space(3))) void*)(p)

constexpr int IMG = 2, H = 384, W = 384, DIM = 16, HID = 192;
constexpr int HP = 386, WP = 386;     // zero-padded hidden
constexpr int KTOT = 1728;            // 9 taps * 192 ch

// ---------------- K0: pack w_qkv [3][3][192][192] f32 -> B^T [n][k] bf16 ----------------
__global__ __launch_bounds__(256) void pack_wqkv(const float* __restrict__ wq,
                                                 __hip_bfloat16* __restrict__ bp) {
    int idx = blockIdx.x * 256 + threadIdx.x;
    if (idx >= HID * KTOT) return;
    int n = idx / KTOT, k = idx - n * KTOT;
    int tap = k / HID, c = k - tap * HID;
    bp[idx] = __float2bfloat16(wq[(tap * HID + c) * HID + n]);
}

// ---------------- K1: hidden = x @ w_hidden, written zero-padded as bf16 ----------------
__global__ __launch_bounds__(256) void hidden_kernel(const float* __restrict__ x,
                                                     const float* __restrict__ wh,
                                                     __hip_bfloat16* __restrict__ hid) {
    __shared__ float wsm[DIM * HID];   // 12 KB
    for (int i = threadIdx.x; i < DIM * HID; i += 256) wsm[i] = wh[i];
    __syncthreads();
    const int total = IMG * HP * WP * HID;
    for (int idx = blockIdx.x * 256 + threadIdx.x; idx < total; idx += gridDim.x * 256) {
        int ch = idx % HID;
        int pp = idx / HID;
        int wp = pp % WP;
        int rest = pp / WP;
        int hp = rest % HP;
        int img = rest / HP;
        float val = 0.f;
        if (hp != 0 && hp != HP - 1 && wp != 0 && wp != WP - 1) {
            const float* xp = x + ((img * H + hp - 1) * W + (wp - 1)) * DIM;
#pragma unroll
            for (int d = 0; d < DIM; ++d) val += xp[d] * wsm[d * HID + ch];
        }
        hid[idx] = __float2bfloat16(val);
    }
}

// ---------------- K2: qkv = conv3x3(hidden) as implicit-GEMM bf16 MFMA ----------------
// M=294912 (pixels), N=192, K=1728. BM=128 (one row of W), BN=192, BK=32.
// 4 waves, wave tile 64x96 (4 x 6 fragments of 16x16).
__global__ __launch_bounds__(256) void conv_qkv(const __hip_bfloat16* __restrict__ hid,
                                                const __hip_bfloat16* __restrict__ bp,
                                                __hip_bfloat16* __restrict__ qkv) {
    __shared__ __align__(16) short As[128 * 32];   // [row][32ch], granule-swizzled
    __shared__ __align__(16) short Bs[192 * 32];   // [n][32k],  granule-swizzled
    int nb = gridDim.x;                 // 2304, divisible by 8
    int bid = blockIdx.x;
    int swz = (bid & 7) * (nb >> 3) + (bid >> 3);   // XCD-bijective swizzle
    int tw = swz % 3, row = swz / 3;    // row in [0,768)
    int img = row / H, h = row - img * H;
    int w0 = tw * 128;
    int t = threadIdx.x;
    int wv = t >> 6, lane = t & 63;
    int wr = wv >> 1, wc = wv & 1;
    f32x4 acc[4][6] = {};

    for (int kk = 0; kk < 54; ++kk) {
        int tap = kk / 6, cb = kk - tap * 6;
        int dy = tap / 3, dx = tap - dy * 3;
        const __hip_bfloat16* abase = hid + ((img * HP + h + dy) * WP + (w0 + dx)) * HID + cb * 32;
        const __hip_bfloat16* bbase = bp + tap * HID + cb * 32;
        __syncthreads();
#pragma unroll
        for (int i = 0; i < 2; ++i) {               // A: 128 rows x 4 granules = 512 slots
            int s = t + i * 256;
            int p = s >> 2, pg = s & 3;
            int lg = pg ^ ((p >> 1) & 3);           // inverse-swizzled source granule
            __builtin_amdgcn_global_load_lds(AS1(abase + p * HID + lg * 8),
                                             AS3(As + (i * 256 + wv * 64) * 8), 16, 0, 0);
        }
#pragma unroll
        for (int i = 0; i < 3; ++i) {               // B: 192 rows x 4 granules = 768 slots
            int s = t + i * 256;
            int n = s >> 2, pg = s & 3;
            int lg = pg ^ ((n >> 1) & 3);
            __builtin_amdgcn_global_load_lds(AS1(bbase + n * KTOT + lg * 8),
                                             AS3(Bs + (i * 256 + wv * 64) * 8), 16, 0, 0);
        }
        __syncthreads();
        bf16x8 af[4], bfr[6];
#pragma unroll
        for (int m = 0; m < 4; ++m) {
            int r = wr * 64 + m * 16 + (lane & 15);
            int g = (lane >> 4) ^ ((r >> 1) & 3);
            af[m] = *(const bf16x8*)(As + r * 32 + g * 8);
        }
#pragma unroll
        for (int n = 0; n < 6; ++n) {
            int r = wc * 96 + n * 16 + (lane & 15);
            int g = (lane >> 4) ^ ((r >> 1) & 3);
            bfr[n] = *(const bf16x8*)(Bs + r * 32 + g * 8);
        }
#pragma unroll
        for (int m = 0; m < 4; ++m)
#pragma unroll
            for (int n = 0; n < 6; ++n)
                acc[m][n] = __builtin_amdgcn_mfma_f32_16x16x32_bf16(af[m], bfr[n], acc[m][n], 0, 0, 0);
    }

    int pix0 = (img * H + h) * W + w0;
#pragma unroll
    for (int m = 0; m < 4; ++m) {
#pragma unroll
        for (int n = 0; n < 6; ++n) {
            int chn = wc * 96 + n * 16 + (lane & 15);
#pragma unroll
            for (int r4 = 0; r4 < 4; ++r4) {
                int prow = wr * 64 + m * 16 + (lane >> 4) * 4 + r4;
                qkv[(pix0 + prow) * HID + chn] = __float2bfloat16(acc[m][n][r4]);
            }
        }
    }
}

// ---------------- K3: per-patch circular conv + LN + gate + 1x1 out conv ----------------
// One block per (img, ph, pw). lane = channel (64), wave = 16-pixel group.
__global__ __launch_bounds__(256) void patch_kernel(const __hip_bfloat16* __restrict__ qkv,
                                                    const float* __restrict__ lns,
                                                    const float* __restrict__ lnb,
                                                    const float* __restrict__ wout,
                                                    float* __restrict__ out) {
    constexpr int QS = 68;                  // row stride (words), 16B-aligned rows
    __shared__ float smem[2 * 64 * QS];     // q then k; later reused as g[64][69]
    __shared__ float wos[64 * 16];
    float* qs = smem;
    float* ksm = smem + 64 * QS;
    int bid = blockIdx.x;
    int pw = bid % 48;
    int tmp = bid / 48;
    int ph = tmp % 48;
    int img = tmp / 48;
    int t = threadIdx.x, wv = t >> 6, lane = t & 63;
    int base_pix = (img * H + ph * 8) * W + pw * 8;

#pragma unroll
    for (int pp = 0; pp < 16; ++pp) {       // stage q,k: coalesced 128B per wave-read
        int p = wv * 16 + pp;
        int pix = base_pix + (p >> 3) * W + (p & 7);
        qs[lane * QS + p] = __bfloat162float(qkv[pix * HID + lane]);
        ksm[lane * QS + p] = __bfloat162float(qkv[pix * HID + 64 + lane]);
    }
    for (int i = t; i < 64 * 16; i += 256) wos[i] = wout[i];
    __syncthreads();

    // circular conv: out[a,b] = sum_{ip,j} q[(a-ip)&7][j] * k[ip][(b-j)&7]
    float acc[16];
#pragma unroll
    for (int pp = 0; pp < 16; ++pp) acc[pp] = 0.f;
#pragma unroll
    for (int ip = 0; ip < 8; ++ip) {
        const float* kr = &ksm[lane * QS + ip * 8];
        float kg[8];
#pragma unroll
        for (int j = 0; j < 8; ++j) kg[j] = kr[j];
        int r0 = (wv * 2 - ip) & 7;
        int r1 = (wv * 2 + 1 - ip) & 7;
        const float* q0p = &qs[lane * QS + r0 * 8];
        const float* q1p = &qs[lane * QS + r1 * 8];
        float q0[8], q1[8];
#pragma unroll
        for (int j = 0; j < 8; ++j) { q0[j] = q0p[j]; q1[j] = q1p[j]; }
#pragma unroll
        for (int pp = 0; pp < 16; ++pp) {
            int b = pp & 7;
#pragma unroll
            for (int j = 0; j < 8; ++j) {
                float qv = (pp < 8) ? q0[j] : q1[j];
                acc[pp] += qv * kg[(b - j) & 7];
            }
        }
    }

    // LayerNorm over channels (= lanes) + v gating
    float scale = lns[lane], bias = lnb[lane];
    float g[16];
#pragma unroll
    for (int pp = 0; pp < 16; ++pp) {
        float val = acc[pp];
        float s = val, ss = val * val;
#pragma unroll
        for (int off = 32; off > 0; off >>= 1) {
            s += __shfl_xor(s, off, 64);
            ss += __shfl_xor(ss, off, 64);
        }
        float mean = s * (1.f / 64.f);
        float var = ss * (1.f / 64.f) - mean * mean;
        float nrm = (val - mean) * rsqrtf(var + 1e-6f) * scale + bias;
        int p = wv * 16 + pp;
        int pix = base_pix + (p >> 3) * W + (p & 7);
        float vv = __bfloat162float(qkv[pix * HID + 128 + lane]);
        g[pp] = nrm * vv;
    }
    __syncthreads();                        // all conv reads of qs/ksm done
    float* gs = smem;                       // [64 px][69] (4416 words <= 8704)
#pragma unroll
    for (int pp = 0; pp < 16; ++pp) {
        int p = wv * 16 + pp;
        gs[p * 69 + lane] = g[pp];
    }
    __syncthreads();

    // final 1x1 conv: 64ch -> 16
    int p = t & 63, og = t >> 6;
    f32x4 o = {0.f, 0.f, 0.f, 0.f};
#pragma unroll
    for (int ch = 0; ch < 64; ++ch) {
        float gv = gs[p * 69 + ch];
        o[0] += gv * wos[ch * 16 + og * 4 + 0];
        o[1] += gv * wos[ch * 16 + og * 4 + 1];
        o[2] += gv * wos[ch * 16 + og * 4 + 2];
        o[3] += gv * wos[ch * 16 + og * 4 + 3];
    }
    int pix = base_pix + (p >> 3) * W + (p & 7);
    *(f32x4*)(out + pix * 16 + og * 4) = o;
}

extern "C" void kernel_launch(void* const* d_in, const int* in_sizes, int n_in,
                              void* d_out, int out_size, void* d_ws, size_t ws_size,
                              hipStream_t stream) {
    const float* x        = (const float*)d_in[0];
    const float* w_hidden = (const float*)d_in[1];
    const float* w_qkv    = (const float*)d_in[2];
    const float* ln_scale = (const float*)d_in[3];
    const float* ln_bias  = (const float*)d_in[4];
    const float* w_out    = (const float*)d_in[5];
    float* out = (float*)d_out;

    char* wsp = (char*)d_ws;
    const size_t HID_BYTES = (size_t)IMG * HP * WP * HID * 2;   // 114,428,928
    const size_t BP_BYTES  = (size_t)HID * KTOT * 2;            // 663,552
    __hip_bfloat16* hid  = (__hip_bfloat16*)wsp;
    __hip_bfloat16* bpck = (__hip_bfloat16*)(wsp + HID_BYTES);
    __hip_bfloat16* qkv  = (__hip_bfloat16*)(wsp + HID_BYTES + BP_BYTES);

    pack_wqkv<<<(HID * KTOT + 255) / 256, 256, 0, stream>>>(w_qkv, bpck);
    hidden_kernel<<<3072, 256, 0, stream>>>(x, w_hidden, hid);
    conv_qkv<<<2304, 256, 0, stream>>>(hid, bpck, qkv);
    patch_kernel<<<IMG * 48 * 48, 256, 0, stream>>>(qkv, ln_scale, ln_bias, w_out, out);
}

// Round 6
// 476.660 us; speedup vs baseline: 1.1104x; 1.1104x over previous
//
#include <hip/hip_runtime.h>
#include <hip/hip_bf16.h>

typedef short bf16x8 __attribute__((ext_vector_type(8)));
typedef short s16x8 __attribute__((ext_vector_type(8)));
typedef float f32x4 __attribute__((ext_vector_type(4)));
typedef unsigned short u16x4 __attribute__((ext_vector_type(4)));

#define AS1(p) (const __attribute__((address_space(1))) void*)(p)
#define AS3(p) (__attribute__((address_space(3))) void*)(p)

constexpr int IMG = 2, H = 384, W = 384, DIM = 16, HID = 192;
constexpr int HP = 386, WP = 386;     // zero-padded hidden
constexpr int KTOT = 1728;            // 9 taps * 192 ch

__device__ inline short f2bf(float v) {
    __hip_bfloat16 b = __float2bfloat16(v);
    short s; __builtin_memcpy(&s, &b, 2); return s;
}
__device__ inline float bf2f(unsigned short u) {
    return __uint_as_float((unsigned)u << 16);
}

// ---------------- K0: pack w_qkv [3][3][192][192] f32 -> B^T [n][k] bf16 ----------------
__global__ __launch_bounds__(256) void pack_wqkv(const float* __restrict__ wq,
                                                 __hip_bfloat16* __restrict__ bp) {
    int idx = blockIdx.x * 256 + threadIdx.x;
    if (idx >= HID * KTOT) return;
    int n = idx / KTOT, k = idx - n * KTOT;
    int tap = k / HID, c = k - tap * HID;
    bp[idx] = __float2bfloat16(wq[(tap * HID + c) * HID + n]);
}

// ---------------- K0b: zero the padded borders of hid ----------------
__global__ __launch_bounds__(256) void border_zero(__hip_bfloat16* __restrict__ hid) {
    int idx = blockIdx.x * 256 + threadIdx.x;
    s16x8 z = {0, 0, 0, 0, 0, 0, 0, 0};
    if (idx < 37056) {                      // top/bottom full rows: 2 img x 2 rows x 9264 v8
        int img = idx / 18528, j = idx - img * 18528;
        int r = (j / 9264) ? (HP - 1) : 0;
        int off = j % 9264;
        *(s16x8*)(hid + ((size_t)(img * HP + r) * WP) * HID + (size_t)off * 8) = z;
    } else if (idx < 74112) {               // side columns: 2 img x 386 rows x 2 cols x 24 v8
        int i = idx - 37056;
        int img = i / 18528, j = i - img * 18528;
        int row = j / 48, jj = j - row * 48;
        int c = jj / 24, off = jj - c * 24;
        *(s16x8*)(hid + ((size_t)((img * HP + row) * WP) + (size_t)c * (WP - 1)) * HID + (size_t)off * 8) = z;
    }
}

// ---------------- K1: hidden = x @ w_hidden via MFMA 16x16x32 (K zero-padded) ----------------
__global__ __launch_bounds__(256) void hidden_mfma(const float* __restrict__ x,
                                                   const float* __restrict__ wh,
                                                   __hip_bfloat16* __restrict__ hid) {
    int t = threadIdx.x, wv = t >> 6, lane = t & 63;
    int m = lane & 15, half = lane >> 4;    // half = k-granule 0..3 (k = half*8+u)
    bf16x8 bfrag[12];
#pragma unroll
    for (int nb = 0; nb < 12; ++nb) {
#pragma unroll
        for (int u = 0; u < 8; ++u) {
            int k = half * 8 + u;
            float val = (k < DIM) ? wh[k * HID + nb * 16 + m] : 0.f;
            bfrag[nb][u] = f2bf(val);
        }
    }
    int wid = blockIdx.x * 4 + wv;
#pragma unroll
    for (int tt = 0; tt < 2; ++tt) {
        int tile = wid * 2 + tt;            // 16-pixel tile, 18432 total
        bf16x8 af = {};
        if (half < 2) {
            const float* xp = x + (size_t)(tile * 16 + m) * DIM + half * 8;
            f32x4 x0 = *(const f32x4*)xp;
            f32x4 x1 = *(const f32x4*)(xp + 4);
#pragma unroll
            for (int u = 0; u < 4; ++u) { af[u] = f2bf(x0[u]); af[4 + u] = f2bf(x1[u]); }
        }
        f32x4 c[12];
#pragma unroll
        for (int nb = 0; nb < 12; ++nb) {
            f32x4 zz = {0.f, 0.f, 0.f, 0.f};
            c[nb] = __builtin_amdgcn_mfma_f32_16x16x32_bf16(af, bfrag[nb], zz, 0, 0, 0);
        }
#pragma unroll
        for (int r = 0; r < 4; ++r) {
            int pix = tile * 16 + half * 4 + r;
            int img = pix / (H * W), rem = pix - img * (H * W);
            int hh = rem / W, ww = rem - hh * W;
            __hip_bfloat16* dst = hid + ((size_t)(img * HP + hh + 1) * WP + (ww + 1)) * HID + m;
#pragma unroll
            for (int nb = 0; nb < 12; ++nb) dst[nb * 16] = __float2bfloat16(c[nb][r]);
        }
    }
}

// ---------------- K2: qkv = conv3x3(hidden), implicit-GEMM bf16 MFMA ----------------
// M=294912, N=192, K=1728. BM=128, BN=192, BK=32. Double-buffered LDS, stage-ahead,
// counted vmcnt(5) + raw s_barrier (no full drain in steady state).
__global__ __launch_bounds__(256) void conv_qkv(const __hip_bfloat16* __restrict__ hid,
                                                const __hip_bfloat16* __restrict__ bp,
                                                __hip_bfloat16* __restrict__ qkv) {
    __shared__ __align__(16) short As[2][128 * 32];   // 2 x 8 KB
    __shared__ __align__(16) short Bs[2][192 * 32];   // 2 x 12 KB
    int nb = gridDim.x;                 // 2304, divisible by 8
    int bid = blockIdx.x;
    int swz = (bid & 7) * (nb >> 3) + (bid >> 3);   // XCD-bijective swizzle
    int tw = swz % 3, row = swz / 3;
    int img = row / H, h = row - img * H;
    int w0 = tw * 128;
    int t = threadIdx.x;
    int wv = t >> 6, lane = t & 63;
    int wr = wv >> 1, wc = wv & 1;
    f32x4 acc[4][6] = {};

    auto stage = [&](int kk, int c) {
        int tap = kk / 6, cb = kk - tap * 6;
        int dy = tap / 3, dx = tap - dy * 3;
        const __hip_bfloat16* abase = hid + ((size_t)(img * HP + h + dy) * WP + (w0 + dx)) * HID + cb * 32;
        const __hip_bfloat16* bbase = bp + tap * HID + cb * 32;
#pragma unroll
        for (int i = 0; i < 2; ++i) {               // A: 128 rows x 4 granules
            int s = t + i * 256;
            int p = s >> 2, pg = s & 3;
            int lg = pg ^ ((p >> 1) & 3);
            __builtin_amdgcn_global_load_lds(AS1(abase + p * HID + lg * 8),
                                             AS3(&As[c][(i * 256 + wv * 64) * 8]), 16, 0, 0);
        }
#pragma unroll
        for (int i = 0; i < 3; ++i) {               // B: 192 rows x 4 granules
            int s = t + i * 256;
            int n = s >> 2, pg = s & 3;
            int lg = pg ^ ((n >> 1) & 3);
            __builtin_amdgcn_global_load_lds(AS1(bbase + n * KTOT + lg * 8),
                                             AS3(&Bs[c][(i * 256 + wv * 64) * 8]), 16, 0, 0);
        }
    };

    stage(0, 0);
#pragma unroll 2
    for (int kk = 0; kk < 54; ++kk) {
        int cur = kk & 1;
        __builtin_amdgcn_s_barrier();               // buf[cur^1] free to overwrite
        if (kk < 53) {
            stage(kk + 1, cur ^ 1);
            asm volatile("s_waitcnt vmcnt(5)" ::: "memory");   // my stage(kk) landed
        } else {
            asm volatile("s_waitcnt vmcnt(0)" ::: "memory");
        }
        __builtin_amdgcn_s_barrier();               // everyone's stage(kk) landed
        __builtin_amdgcn_sched_barrier(0);

        const short* Asc = &As[cur][0];
        const short* Bsc = &Bs[cur][0];
        bf16x8 af[4], bfr[6];
#pragma unroll
        for (int m = 0; m < 4; ++m) {
            int r = wr * 64 + m * 16 + (lane & 15);
            int g = (lane >> 4) ^ ((r >> 1) & 3);
            af[m] = *(const bf16x8*)(Asc + r * 32 + g * 8);
        }
#pragma unroll
        for (int n = 0; n < 6; ++n) {
            int r = wc * 96 + n * 16 + (lane & 15);
            int g = (lane >> 4) ^ ((r >> 1) & 3);
            bfr[n] = *(const bf16x8*)(Bsc + r * 32 + g * 8);
        }
#pragma unroll
        for (int m = 0; m < 4; ++m)
#pragma unroll
            for (int n = 0; n < 6; ++n)
                acc[m][n] = __builtin_amdgcn_mfma_f32_16x16x32_bf16(af[m], bfr[n], acc[m][n], 0, 0, 0);
    }

    int pix0 = (img * H + h) * W + w0;
#pragma unroll
    for (int m = 0; m < 4; ++m) {
#pragma unroll
        for (int n = 0; n < 6; ++n) {
            int chn = wc * 96 + n * 16 + (lane & 15);
#pragma unroll
            for (int r4 = 0; r4 < 4; ++r4) {
                int prow = wr * 64 + m * 16 + (lane >> 4) * 4 + r4;
                qkv[(size_t)(pix0 + prow) * HID + chn] = __float2bfloat16(acc[m][n][r4]);
            }
        }
    }
}

// ---------------- K3: per-patch circular conv + LN + gate + 1x1 out conv ----------------
// LDS in [px][ch] orientation (stride 68): every conv read is fixed-px, lane=ch stride-1
// -> conflict-free. LN via LDS transpose (no 64-wide shuffles).
__global__ __launch_bounds__(256) void patch_kernel(const __hip_bfloat16* __restrict__ qkv,
                                                    const float* __restrict__ lns,
                                                    const float* __restrict__ lnb,
                                                    const float* __restrict__ wout,
                                                    float* __restrict__ out) {
    constexpr int ST = 68;                    // f32 words / ushorts per px row (16B aligned)
    __shared__ __align__(16) float smem[2 * 64 * ST];   // qs | ks ; qs reused as gs
    __shared__ __align__(16) unsigned short vsm[64 * ST];
    __shared__ float wos[64 * 16];
    __shared__ float lnSs[64], lnBs[64], meanA[64], rsigA[64];
    float* qs = smem;
    float* ks = smem + 64 * ST;

    int bid = blockIdx.x;
    int pw = bid % 48;
    int tmp = bid / 48;
    int ph = tmp % 48;
    int img = tmp / 48;
    int t = threadIdx.x, wv = t >> 6, lane = t & 63;
    int base_pix = (img * H + ph * 8) * W + pw * 8;

    // ---- stage q,k,v: ushort4 vectorized, coalesced 384B runs ----
#pragma unroll
    for (int i = 0; i < 12; ++i) {
        int idx = i * 256 + t;                // 64 px x 48 ch4-groups
        int ch4 = idx % 48, px = idx / 48;
        int pix = base_pix + (px >> 3) * W + (px & 7);
        u16x4 v4 = *(const u16x4*)((const unsigned short*)qkv + (size_t)pix * HID + ch4 * 4);
        if (ch4 < 16) {
            f32x4 f = {bf2f(v4[0]), bf2f(v4[1]), bf2f(v4[2]), bf2f(v4[3])};
            *(f32x4*)(qs + px * ST + ch4 * 4) = f;
        } else if (ch4 < 32) {
            f32x4 f = {bf2f(v4[0]), bf2f(v4[1]), bf2f(v4[2]), bf2f(v4[3])};
            *(f32x4*)(ks + px * ST + (ch4 - 16) * 4) = f;
        } else {
            *(u16x4*)(vsm + px * ST + (ch4 - 32) * 4) = v4;
        }
    }
    for (int i = t; i < 64 * 16; i += 256) wos[i] = wout[i];
    if (t < 64) { lnSs[t] = lns[t]; lnBs[t] = lnb[t]; }
    __syncthreads();

    // ---- circular conv: out[a,b] = sum_{ip,j} q[(a-ip)&7][j] * k[ip][(b-j)&7], ch = lane ----
    float acc[16];
#pragma unroll
    for (int pp = 0; pp < 16; ++pp) acc[pp] = 0.f;
#pragma unroll
    for (int ip = 0; ip < 8; ++ip) {
        float kg[8];
#pragma unroll
        for (int j = 0; j < 8; ++j) kg[j] = ks[(ip * 8 + j) * ST + lane];
        int r0 = (wv * 2 - ip) & 7;
        int r1 = (wv * 2 + 1 - ip) & 7;
        float q0[8], q1[8];
#pragma unroll
        for (int j = 0; j < 8; ++j) {
            q0[j] = qs[(r0 * 8 + j) * ST + lane];
            q1[j] = qs[(r1 * 8 + j) * ST + lane];
        }
#pragma unroll
        for (int pp = 0; pp < 16; ++pp) {
            int b = pp & 7;
#pragma unroll
            for (int j = 0; j < 8; ++j) {
                float qv = (pp < 8) ? q0[j] : q1[j];
                acc[pp] += qv * kg[(b - j) & 7];
            }
        }
    }
    __syncthreads();                          // all conv reads of qs done

    // ---- write raw conv to gs[px][ch] (reuse qs region) ----
    float* gs = qs;
#pragma unroll
    for (int pp = 0; pp < 16; ++pp) {
        int p = wv * 16 + pp;
        gs[p * ST + lane] = acc[pp];          // lanes stride-1: conflict-free
    }
    __syncthreads();

    // ---- per-pixel LN stats: 4 threads per pixel ----
    {
        int px = t >> 2, qq = t & 3;
        float s = 0.f, ss = 0.f;
#pragma unroll
        for (int u = 0; u < 16; ++u) {
            float v = gs[px * ST + qq * 16 + u];
            s += v; ss += v * v;
        }
        s  += __shfl_xor(s, 1, 64);  ss += __shfl_xor(ss, 1, 64);
        s  += __shfl_xor(s, 2, 64);  ss += __shfl_xor(ss, 2, 64);
        if (qq == 0) {
            float mean = s * (1.f / 64.f);
            float var = ss * (1.f / 64.f) - mean * mean;
            meanA[px] = mean;
            rsigA[px] = rsqrtf(var + 1e-6f);
        }
    }
    __syncthreads();

    // ---- fused LN + gate + 1x1 conv (64ch -> 16) ----
    int p = t & 63, og = t >> 6;
    float mean = meanA[p], rsig = rsigA[p];
    f32x4 o = {0.f, 0.f, 0.f, 0.f};
#pragma unroll
    for (int c4 = 0; c4 < 16; ++c4) {
        f32x4 graw = *(const f32x4*)(gs + p * ST + c4 * 4);       // b128, conflict-free
        u16x4 vv = *(const u16x4*)(vsm + p * ST + c4 * 4);        // b64, conflict-free
        f32x4 s4 = *(const f32x4*)(lnSs + c4 * 4);                // broadcast
        f32x4 b4 = *(const f32x4*)(lnBs + c4 * 4);
#pragma unroll
        for (int u = 0; u < 4; ++u) {
            int ch = c4 * 4 + u;
            float vf = bf2f((unsigned short)vv[u]);
            float g = ((graw[u] - mean) * rsig * s4[u] + b4[u]) * vf;
            f32x4 w4 = *(const f32x4*)(wos + ch * 16 + og * 4);   // broadcast
            o[0] += g * w4[0]; o[1] += g * w4[1];
            o[2] += g * w4[2]; o[3] += g * w4[3];
        }
    }
    int pix = base_pix + (p >> 3) * W + (p & 7);
    *(f32x4*)(out + (size_t)pix * 16 + og * 4) = o;
}

extern "C" void kernel_launch(void* const* d_in, const int* in_sizes, int n_in,
                              void* d_out, int out_size, void* d_ws, size_t ws_size,
                              hipStream_t stream) {
    const float* x        = (const float*)d_in[0];
    const float* w_hidden = (const float*)d_in[1];
    const float* w_qkv    = (const float*)d_in[2];
    const float* ln_scale = (const float*)d_in[3];
    const float* ln_bias  = (const float*)d_in[4];
    const float* w_out    = (const float*)d_in[5];
    float* out = (float*)d_out;

    char* wsp = (char*)d_ws;
    const size_t HID_BYTES = (size_t)IMG * HP * WP * HID * 2;   // 114,428,928
    const size_t BP_BYTES  = (size_t)HID * KTOT * 2;            // 663,552
    __hip_bfloat16* hid  = (__hip_bfloat16*)wsp;
    __hip_bfloat16* bpck = (__hip_bfloat16*)(wsp + HID_BYTES);
    __hip_bfloat16* qkv  = (__hip_bfloat16*)(wsp + HID_BYTES + BP_BYTES);

    pack_wqkv<<<(HID * KTOT + 255) / 256, 256, 0, stream>>>(w_qkv, bpck);
    border_zero<<<290, 256, 0, stream>>>(hid);
    hidden_mfma<<<2304, 256, 0, stream>>>(x, w_hidden, hid);
    conv_qkv<<<2304, 256, 0, stream>>>(hid, bpck, qkv);
    patch_kernel<<<IMG * 48 * 48, 256, 0, stream>>>(qkv, ln_scale, ln_bias, w_out, out);
}